// Round 8
// baseline (5818.290 us; speedup 1.0000x reference)
//
#include <hip/hip_runtime.h>
#include <stdint.h>

// 128x128 block tile, 4 waves (256 threads), per-wave 64x64 (proven geometry).
// Round 8: A-in-REGISTERS (per-lane global dwordx4, depth-1 prefetch; A-slices
// are L2-resident ~200cy) + B-in-LDS 4-slot rotating prefetch (depth-3 cover
// ~600+cy >= L3 latency) + ONE barrier + counted vmcnt(12) per iter.
// Rationale: 7 rounds showed the 2-phase structure pinned at 614 TF (= m233's
// 607 ceiling) because all waves in a block drain together per iter. This
// makes each block SELF-covering: B(i+1) is drained by the vmcnt(12) wait
// (newest-12 in flight = B(i+3)'s 4 + A(i+1)'s 8, FIFO), so prefetches span
// barriers. Slot overwritten at iter i was last read at iter i-1 behind a
// barrier -> race-free by construction. B staging/swizzle identical to the
// verified BK=64 path (0 conflicts); numerics bit-identical.
#define BM 128
#define BN 128
#define BK 64
#define NTHREADS 256
#define SLOT_E 8192              // B slot: 128x64 bf16 = 16 KB; 4 slots = 64 KB

typedef __bf16 bf16x8 __attribute__((ext_vector_type(8)));
typedef float f32x4 __attribute__((ext_vector_type(4)));

__device__ __forceinline__ float bf2f(uint16_t u) {
  union { uint32_t u32; float f; } x; x.u32 = ((uint32_t)u) << 16; return x.f;
}
// round-to-nearest-even f32 -> bf16 (finite values only)
__device__ __forceinline__ uint16_t f2bf(float f) {
  uint32_t x = __float_as_uint(f);
  uint32_t r = (x + 0x7FFFu + ((x >> 16) & 1u)) >> 16;
  return (uint16_t)r;
}

// async global->LDS, 16B per lane. LDS dest is wave-uniform base + lane*16B.
__device__ __forceinline__ void gload_lds16(const uint16_t* g, uint16_t* l) {
  __builtin_amdgcn_global_load_lds(
      (const __attribute__((address_space(1))) uint32_t*)g,
      (__attribute__((address_space(3))) uint32_t*)l, 16, 0, 0);
}

__device__ __forceinline__ void waitv12() {
  asm volatile("s_waitcnt vmcnt(12)" ::: "memory");
}
__device__ __forceinline__ void waitv0() {
  asm volatile("s_waitcnt vmcnt(0)" ::: "memory");
}
__device__ __forceinline__ void sbar() {
  __builtin_amdgcn_s_barrier();
  __builtin_amdgcn_sched_barrier(0);   // pin: no ds_read hoists above barrier
}

// C(128x128 at m0,n0) += A(MxK row-major bf16) * Bt(NxK row-major bf16)^T
// B staged via gload_lds into 4 rotating slots, XOR-swizzled exactly as the
// verified baseline: LDS[row][slot] holds global chunk (slot ^ (row&7));
// read offset sw = (kc ^ (ln&7))*8, kc = kk*4 + (ln>>4). 0 bank conflicts.
// A fragments loaded straight to VGPRs: lane ln, frag (mt,kk) reads
// A[m0 + wr*64 + mt*16 + (ln&15)][i*64 + (kk*4 + (ln>>4))*8 ..+7] — the same
// logical elements the LDS path delivered -> bit-identical MFMA inputs.
__device__ __forceinline__ void gemm_tile(
    const uint16_t* __restrict__ A, int ldA,
    const uint16_t* __restrict__ Bt, int ldB,
    int m0, int n0, int K,
    uint16_t* lds, f32x4 acc[4][4])
{
  const int t  = threadIdx.x;
  const int ln = t & 63;
  const int wv = t >> 6;
  const int wr = wv >> 1, wc = wv & 1;

  // B staging: thread t -> rows (t>>3)+32c, global chunk gc=(t&7)^(row&7)
  // into LDS slot-chunk (t&7); dest (t<<3) is lane-contiguous per wave.
  const int brow = t >> 3;
  const int gc   = (t & 7) ^ (brow & 7);
  const uint16_t* gB = Bt + (size_t)(n0 + brow) * ldB + (gc << 3);

  // A per-lane fragment base pointers (one per mt; kk via +32 elems).
  const uint16_t* pA[4];
#pragma unroll
  for (int mt = 0; mt < 4; ++mt)
    pA[mt] = A + (size_t)(m0 + (wr << 6) + (mt << 4) + (ln & 15)) * ldA
               + ((ln >> 4) << 3);

  auto STAGE = [&](int i) {
    uint16_t* lb = lds + ((i & 3) * SLOT_E) + (t << 3);
    const uint16_t* gb = gB + (size_t)i * BK;
#pragma unroll
    for (int c = 0; c < 4; ++c)
      gload_lds16(gb + (size_t)(c * 32) * ldB, lb + c * 2048);
  };

  auto LOADA = [&](int i, bf16x8 (&af)[4][2]) {
#pragma unroll
    for (int mt = 0; mt < 4; ++mt) {
      af[mt][0] = *(const bf16x8*)(pA[mt] + (size_t)i * BK);
      af[mt][1] = *(const bf16x8*)(pA[mt] + (size_t)i * BK + 32);
    }
  };

  auto COMPUTE = [&](int i, const bf16x8 (&af)[4][2]) {
    const uint16_t* bB = lds + ((i & 3) * SLOT_E);
#pragma unroll
    for (int kk = 0; kk < 2; ++kk) {
      const int kc  = (kk << 2) + (ln >> 4);
      const int swz = (kc ^ (ln & 7)) << 3;
      bf16x8 bfr[4];
#pragma unroll
      for (int nq = 0; nq < 4; ++nq)
        bfr[nq] = *(const bf16x8*)&bB[((wc << 6) + (nq << 4) + (ln & 15)) * BK + swz];
      __builtin_amdgcn_s_setprio(1);
#pragma unroll
      for (int mt = 0; mt < 4; ++mt)
#pragma unroll
        for (int nq = 0; nq < 4; ++nq)
          acc[mt][nq] = __builtin_amdgcn_mfma_f32_16x16x32_bf16(
              af[mt][kk], bfr[nq], acc[mt][nq], 0, 0, 0);
      __builtin_amdgcn_s_setprio(0);
    }
  };

  const int nt = K >> 6;                 // 32 or 16 (always even, >= 4)
  bf16x8 afA[4][2], afB[4][2];

  // prologue: 3 B-slots in flight + A(0); one-time full drain.
  STAGE(0); STAGE(1); STAGE(2);
  LOADA(0, afA);
  waitv0(); sbar();

  // steady state, unrolled x2 for static af double-buffer (rule #20).
  // Per body: issue B(i+3) + A(i+1); compute(i); vmcnt(12) keeps the 12
  // newest ops (B(i+3)+A(i+1)) in flight while guaranteeing B(i+1) landed.
  for (int i = 0; i < nt; i += 2) {
    if (i + 3 < nt) STAGE(i + 3);
    LOADA(i + 1, afB);                   // i+1 <= nt-1 always
    COMPUTE(i, afA);
    waitv12(); sbar();

    if (i + 4 < nt) STAGE(i + 4);
    if (i + 2 < nt) LOADA(i + 2, afA);
    COMPUTE(i + 1, afB);
    waitv12(); sbar();
  }
  // loop ends with a barrier -> slots safe for the next gemm_tile call.
}

// One Jacobi relaxation step, 3 GEMMs fused in one 640-block grid.
//
// 2-D XCD partition (round 3 — cut HBM fetch 31%): x = b&7; g=x&3 owns the
// bm quarter, h=x>>2 owns the bn half. Per-XCD weight demand 12 MB, state
// slice 2-5 MB (L2-resident -> A-reg loads are L2 hits).
//
// Heavy-first (LPT) j-map — 64KB LDS caps 2 blocks/CU, so dispatch order
// now matters for the tail:
//  j<32  (mode 1): pre1 = s2 @ W1^T + s0 @ W0  (pass1 W1b native, pass2 W0Tb)
//  j<48  (mode 0): pre0 = s1 @ W0^T            (Bt = W0b native)
//  else  (mode 2): pre2 = s1 @ W1              (Bt = W1Tb)
// fp32 masters (in d_out) updated in place; bf16 shadows double-buffered.
__global__ void __launch_bounds__(NTHREADS, 2) step_kernel(
    const uint16_t* __restrict__ s0b_c, const uint16_t* __restrict__ s1b_c,
    const uint16_t* __restrict__ s2b_c,
    uint16_t* __restrict__ s0b_n, uint16_t* __restrict__ s1b_n,
    uint16_t* __restrict__ s2b_n,
    const uint16_t* __restrict__ W0b, const uint16_t* __restrict__ W0Tb,
    const uint16_t* __restrict__ W1b, const uint16_t* __restrict__ W1Tb,
    const float* __restrict__ b0, const float* __restrict__ b1,
    const float* __restrict__ c2f,
    float* __restrict__ s0f, float* __restrict__ s1f, float* __restrict__ s2f)
{
  __shared__ uint16_t lds[4 * SLOT_E];   // 64 KB: 4 rotating B slots

  f32x4 acc[4][4];
  const f32x4 z = {0.f, 0.f, 0.f, 0.f};
#pragma unroll
  for (int i = 0; i < 4; ++i)
#pragma unroll
    for (int j = 0; j < 4; ++j) acc[i][j] = z;

  const int x = blockIdx.x & 7;    // XCD (dispatch round-robin heuristic)
  const int j = blockIdx.x >> 3;   // 0..79 within XCD
  const int g = x & 3;             // bm-group: bm in {4g..4g+3}
  const int h = x >> 2;            // bn-half
  int mode, bm, bn;
  if (j < 32) {                    // heavy first (LPT under 2-block cap)
    mode = 1; bm = (g << 2) + (j >> 3); bn = (h << 3) + (j & 7);
    gemm_tile(s2b_c, 2048, W1b, 2048, bm * BM, bn * BN, 2048, lds, acc);
    gemm_tile(s0b_c, 1024, W0Tb, 1024, bm * BM, bn * BN, 1024, lds, acc);
  } else if (j < 48) {
    const int l = j - 32;
    mode = 0; bm = (g << 2) + (l >> 2); bn = (h << 2) + (l & 3);
    gemm_tile(s1b_c, 2048, W0b, 2048, bm * BM, bn * BN, 2048, lds, acc);
  } else {
    const int u = j - 48;
    mode = 2; bm = (g << 2) + (u >> 3); bn = (h << 3) + (u & 7);
    gemm_tile(s1b_c, 2048, W1Tb, 2048, bm * BM, bn * BN, 2048, lds, acc);
  }

  const int t = threadIdx.x, wv = t >> 6, ln = t & 63;
  const int wr = wv >> 1, wc = wv & 1;
  const int rb = (ln >> 4) << 2, cc = ln & 15;
  const int m0 = bm * BM, n0 = bn * BN;

#pragma unroll
  for (int mt = 0; mt < 4; ++mt) {
#pragma unroll
    for (int nt = 0; nt < 4; ++nt) {
      const int gn = n0 + (wc << 6) + (nt << 4) + cc;
      float add = 0.f;
      if (mode == 0) add = b0[gn];
      else if (mode == 1) add = b1[gn];
#pragma unroll
      for (int r = 0; r < 4; ++r) {
        const int gm = m0 + (wr << 6) + (mt << 4) + rb + r;
        const float pre = acc[mt][nt][r];
        if (mode == 0) {
          const size_t ix = (size_t)gm * 1024 + gn;
          float nv = 0.8f * s0f[ix] + 0.2f * (pre + add);
          nv = fminf(fmaxf(nv, 0.f), 1.f);
          s0f[ix] = nv;
          s0b_n[ix] = f2bf(nv);
        } else if (mode == 1) {
          const size_t ix = (size_t)gm * 2048 + gn;
          float nv = 0.8f * s1f[ix] + 0.2f * (pre + add);
          nv = fminf(fmaxf(nv, 0.f), 1.f);
          s1f[ix] = nv;
          s1b_n[ix] = f2bf(nv);
        } else {
          const size_t ix = (size_t)gm * 2048 + gn;
          float nv = 0.8f * s2f[ix] + 0.2f * (pre + c2f[ix]);
          nv = fminf(fmaxf(nv, 0.f), 1.f);
          s2f[ix] = nv;
          s2b_n[ix] = f2bf(nv);
        }
      }
    }
  }
}

// c2 = data @ W2^T + b2 (step-invariant), fp32 result.
__global__ void __launch_bounds__(NTHREADS, 2) c2_kernel(
    const uint16_t* __restrict__ datab,
    const uint16_t* __restrict__ W2b,
    const float* __restrict__ b2,
    float* __restrict__ c2f)
{
  __shared__ uint16_t lds[4 * SLOT_E];
  f32x4 acc[4][4];
  const f32x4 z = {0.f, 0.f, 0.f, 0.f};
#pragma unroll
  for (int i = 0; i < 4; ++i)
#pragma unroll
    for (int j = 0; j < 4; ++j) acc[i][j] = z;

  const int bm = blockIdx.x >> 4, bn = blockIdx.x & 15;
  gemm_tile(datab, 2048, W2b, 2048, bm * BM, bn * BN, 2048, lds, acc);

  const int t = threadIdx.x, wv = t >> 6, ln = t & 63;
  const int wr = wv >> 1, wc = wv & 1;
  const int rb = (ln >> 4) << 2, cc = ln & 15;
  const int m0 = bm * BM, n0 = bn * BN;
#pragma unroll
  for (int mt = 0; mt < 4; ++mt)
#pragma unroll
    for (int nt = 0; nt < 4; ++nt) {
      const int gn = n0 + (wc << 6) + (nt << 4) + cc;
      const float bb = b2[gn];
#pragma unroll
      for (int r = 0; r < 4; ++r) {
        const int gm = m0 + (wr << 6) + (mt << 4) + rb + r;
        c2f[(size_t)gm * 2048 + gn] = acc[mt][nt][r] + bb;
      }
    }
}

// fp32 -> bf16 straight convert, 4 elems/thread.
__global__ void conv_k(const float* __restrict__ src, uint16_t* __restrict__ dst)
{
  const size_t i4 = ((size_t)blockIdx.x * 256 + threadIdx.x) << 2;
  const float4 v = *(const float4*)(src + i4);
  ushort4 o;
  o.x = f2bf(v.x); o.y = f2bf(v.y); o.z = f2bf(v.z); o.w = f2bf(v.w);
  *(ushort4*)(dst + i4) = o;
}

// fp32 -> bf16 transposed: dst[c*ldD + r] = bf16(src[r*ldS + c]).
__global__ void convT_k(const float* __restrict__ src, uint16_t* __restrict__ dst,
                        int ldS, int ldD)
{
  __shared__ uint16_t tile[32][33];
  const int r0 = blockIdx.y * 32, c0 = blockIdx.x * 32;
  tile[threadIdx.y][threadIdx.x] =
      f2bf(src[(size_t)(r0 + threadIdx.y) * ldS + c0 + threadIdx.x]);
  __syncthreads();
  dst[(size_t)(c0 + threadIdx.y) * ldD + r0 + threadIdx.x] = tile[threadIdx.x][threadIdx.y];
}

// fp32 input -> fp32 master (in d_out) + bf16 shadow. 4 elems/thread.
__global__ void init_state(const float* __restrict__ in,
                           float* __restrict__ sf, uint16_t* __restrict__ sb)
{
  const size_t i4 = ((size_t)blockIdx.x * 256 + threadIdx.x) << 2;
  const float4 v = *(const float4*)(in + i4);
  *(float4*)(sf + i4) = v;
  ushort4 o;
  o.x = f2bf(v.x); o.y = f2bf(v.y); o.z = f2bf(v.z); o.w = f2bf(v.w);
  *(ushort4*)(sb + i4) = o;
}

extern "C" void kernel_launch(void* const* d_in, const int* in_sizes, int n_in,
                              void* d_out, int out_size, void* d_ws, size_t ws_size,
                              hipStream_t stream) {
  const float* s0   = (const float*)d_in[0];
  const float* s1   = (const float*)d_in[1];
  const float* s2   = (const float*)d_in[2];
  const float* data = (const float*)d_in[3];
  const float* W0   = (const float*)d_in[4];
  const float* b0   = (const float*)d_in[5];
  const float* W1   = (const float*)d_in[6];
  const float* b1   = (const float*)d_in[7];
  const float* W2   = (const float*)d_in[8];
  const float* b2   = (const float*)d_in[9];

  // fp32 masters live directly in d_out: [s0 | s1 | s2].
  float* s0f = (float*)d_out;
  float* s1f = s0f + 2048ull * 1024;
  float* s2f = s1f + 2048ull * 2048;

  char* ws = (char*)d_ws;
  size_t off = 0;
  auto alloc = [&](size_t bytes) -> char* {
    char* p = ws + off; off += (bytes + 255) & ~(size_t)255; return p;
  };
  uint16_t* W0b    = (uint16_t*)alloc(1024ull * 2048 * 2);
  uint16_t* W0Tb   = (uint16_t*)alloc(2048ull * 1024 * 2);
  uint16_t* W1b    = (uint16_t*)alloc(2048ull * 2048 * 2);
  uint16_t* W1Tb   = (uint16_t*)alloc(2048ull * 2048 * 2);
  float*    c2f    = (float*)   alloc(2048ull * 2048 * 4);
  uint16_t* s0b[2] = { (uint16_t*)alloc(2048ull * 1024 * 2),
                       (uint16_t*)alloc(2048ull * 1024 * 2) };
  uint16_t* s1b[2] = { (uint16_t*)alloc(2048ull * 2048 * 2),
                       (uint16_t*)alloc(2048ull * 2048 * 2) };
  uint16_t* s2b[2] = { (uint16_t*)alloc(2048ull * 2048 * 2),
                       (uint16_t*)alloc(2048ull * 2048 * 2) };
  (void)ws_size; (void)in_sizes; (void)n_in; (void)out_size;

  // --- one-time weight prep (fp32 -> bf16) ---
  conv_k<<<1024 * 2048 / 1024, 256, 0, stream>>>(W0, W0b);
  conv_k<<<2048 * 2048 / 1024, 256, 0, stream>>>(W1, W1b);
  dim3 tb(32, 32);
  convT_k<<<dim3(64, 32), tb, 0, stream>>>(W0, W0Tb, 2048, 1024);
  convT_k<<<dim3(64, 64), tb, 0, stream>>>(W1, W1Tb, 2048, 2048);
  // data, W2 -> bf16 into step-"next" shadow buffers (fully overwritten by step 0
  // epilogue before step 1 reads them — safe temps).
  conv_k<<<2048 * 2048 / 1024, 256, 0, stream>>>(data, s1b[1]);
  conv_k<<<2048 * 2048 / 1024, 256, 0, stream>>>(W2, s2b[1]);
  c2_kernel<<<256, NTHREADS, 0, stream>>>(s1b[1], s2b[1], b2, c2f);

  // --- state init: fp32 masters (in d_out) + bf16 shadows ---
  init_state<<<2048 * 1024 / 1024, 256, 0, stream>>>(s0, s0f, s0b[0]);
  init_state<<<2048 * 2048 / 1024, 256, 0, stream>>>(s1, s1f, s1b[0]);
  init_state<<<2048 * 2048 / 1024, 256, 0, stream>>>(s2, s2f, s2b[0]);

  // --- 30 Jacobi relaxation steps, double-buffered bf16 shadows ---
  for (int it = 0; it < 30; ++it) {
    const int c = it & 1, n = c ^ 1;
    step_kernel<<<640, NTHREADS, 0, stream>>>(
        s0b[c], s1b[c], s2b[c], s0b[n], s1b[n], s2b[n],
        W0b, W0Tb, W1b, W1Tb, b0, b1, c2f, s0f, s1f, s2f);
  }
  // masters already in d_out — no output kernel needed.
}

// Round 9
// 2388.194 us; speedup vs baseline: 2.4363x; 2.4363x over previous
//
#include <hip/hip_runtime.h>
#include <stdint.h>

// REVERT to the verified session optimum (round-3 kernel, 2438 us; best-ever
// 2423 within noise). Eight rounds of structural variation all measured
// neutral-or-worse: balance (R1/R2), traffic -31% (R3, time-neutral),
// blocks/CU x2 (R4), waves/SIMD x2 (R5), counted-vmcnt pipelines in three
// shapes (R6/R7/R8). This 2-phase 128^2 structure runs at its documented
// ceiling (614 TF effective = m233's 607 TF 2-phase limit); the 8-phase 256^2
// escape is geometry-incompatible here (160 tiles -> 62% CU coverage).
#define BM 128
#define BN 128
#define BK 64

typedef __bf16 bf16x8 __attribute__((ext_vector_type(8)));
typedef float f32x4 __attribute__((ext_vector_type(4)));

__device__ __forceinline__ float bf2f(uint16_t u) {
  union { uint32_t u32; float f; } x; x.u32 = ((uint32_t)u) << 16; return x.f;
}
// round-to-nearest-even f32 -> bf16 (finite values only)
__device__ __forceinline__ uint16_t f2bf(float f) {
  uint32_t x = __float_as_uint(f);
  uint32_t r = (x + 0x7FFFu + ((x >> 16) & 1u)) >> 16;
  return (uint16_t)r;
}

// async global->LDS, 16B per lane. LDS dest is wave-uniform base + lane*16B;
// our per-lane lds ptr (16B * t) is exactly lane-contiguous per wave.
__device__ __forceinline__ void gload_lds16(const uint16_t* g, uint16_t* l) {
  __builtin_amdgcn_global_load_lds(
      (const __attribute__((address_space(1))) uint32_t*)g,
      (__attribute__((address_space(3))) uint32_t*)l, 16, 0, 0);
}

// C(BMxBN at m0,n0) += A(MxK row-major bf16) * Bt(NxK row-major bf16)^T
// Staging: global_load_lds width=16 (m97 path). LDS ldsA[m][kc] with XOR swizzle:
// LDS[row][slot] holds global 16B-chunk (slot ^ (row&7)) -> frag ds_read_b128
// spreads over all 32 banks (2-way aliasing = free) instead of 16-way on banks 0-3.
// Values at each logical (row,k) are unchanged -> bit-identical numerics.
// Wave (wr,wc) owns a 64x64 quadrant; 4x4 grid of 16x16x32 MFMA tiles.
__device__ __forceinline__ void gemm_tile(
    const uint16_t* __restrict__ A, int ldA,
    const uint16_t* __restrict__ Bt, int ldB,
    int m0, int n0, int K,
    uint16_t* ldsA, uint16_t* ldsB, f32x4 acc[4][4])
{
  const int t  = threadIdx.x;
  const int ln = t & 63;
  const int wv = t >> 6;
  const int wr = wv >> 1, wc = wv & 1;

  // thread t stages rows (t>>3)+32c; fetches global chunk gc=(t&7)^(row&7)
  // into LDS slot (t&7). (row+32c)&7 == row&7, so gc is loop-invariant.
  const int row = t >> 3;
  const int gc  = (t & 7) ^ (row & 7);
  const uint16_t* ga = A  + (size_t)(m0 + row) * ldA + (gc << 3);
  const uint16_t* gb = Bt + (size_t)(n0 + row) * ldB + (gc << 3);
  uint16_t* la = ldsA + (t << 3);   // 16B * t : lane-contiguous per wave
  uint16_t* lb = ldsB + (t << 3);

  for (int kt = 0; kt < K; kt += BK) {
    __syncthreads();               // previous tile's readers done
#pragma unroll
    for (int c = 0; c < 4; ++c) {
      gload_lds16(ga + (size_t)(c * 32) * ldA, la + c * 2048);
      gload_lds16(gb + (size_t)(c * 32) * ldB, lb + c * 2048);
    }
    ga += BK; gb += BK;
    __syncthreads();               // barrier drains vmcnt -> staging visible

#pragma unroll
    for (int kk = 0; kk < 2; ++kk) {
      const int kc = (kk << 2) + (ln >> 4);       // logical 16B chunk in K
      const int sw = (kc ^ (ln & 7)) << 3;        // swizzled elem offset (row&7==ln&7)
      bf16x8 af[4], bfr[4];
#pragma unroll
      for (int mt = 0; mt < 4; ++mt)
        af[mt] = *(const bf16x8*)&ldsA[((wr << 6) + (mt << 4) + (ln & 15)) * BK + sw];
#pragma unroll
      for (int nt = 0; nt < 4; ++nt)
        bfr[nt] = *(const bf16x8*)&ldsB[((wc << 6) + (nt << 4) + (ln & 15)) * BK + sw];
#pragma unroll
      for (int mt = 0; mt < 4; ++mt)
#pragma unroll
        for (int nt = 0; nt < 4; ++nt)
          acc[mt][nt] = __builtin_amdgcn_mfma_f32_16x16x32_bf16(
              af[mt], bfr[nt], acc[mt][nt], 0, 0, 0);
    }
  }
}

// One Jacobi relaxation step, 3 GEMMs fused in one 640-block grid.
//
// 2-D XCD partition (round 3 — cut HBM fetch 31%): x = b&7; g=x&3 owns the
// bm quarter, h=x>>2 owns the bn half. Per-XCD weight demand 12 MB, state
// slice ~5 MB. Correctness is mapping-independent.
//
//  j<16  (mode 0): pre0 = s1 @ W0^T            (Bt = W0b native)
//  j<48  (mode 1): pre1 = s2 @ W1^T + s0 @ W0  (pass1 W1b native, pass2 W0Tb)
//  else  (mode 2): pre2 = s1 @ W1              (Bt = W1Tb)
// fp32 masters (in d_out) updated in place; bf16 shadows double-buffered.
__global__ void step_kernel(
    const uint16_t* __restrict__ s0b_c, const uint16_t* __restrict__ s1b_c,
    const uint16_t* __restrict__ s2b_c,
    uint16_t* __restrict__ s0b_n, uint16_t* __restrict__ s1b_n,
    uint16_t* __restrict__ s2b_n,
    const uint16_t* __restrict__ W0b, const uint16_t* __restrict__ W0Tb,
    const uint16_t* __restrict__ W1b, const uint16_t* __restrict__ W1Tb,
    const float* __restrict__ b0, const float* __restrict__ b1,
    const float* __restrict__ c2f,
    float* __restrict__ s0f, float* __restrict__ s1f, float* __restrict__ s2f)
{
  __shared__ uint16_t ldsA[BM * BK];
  __shared__ uint16_t ldsB[BN * BK];

  f32x4 acc[4][4];
  const f32x4 z = {0.f, 0.f, 0.f, 0.f};
#pragma unroll
  for (int i = 0; i < 4; ++i)
#pragma unroll
    for (int j = 0; j < 4; ++j) acc[i][j] = z;

  const int x = blockIdx.x & 7;    // XCD (dispatch round-robin heuristic)
  const int j = blockIdx.x >> 3;   // 0..79 within XCD
  const int g = x & 3;             // bm-group: bm in {4g..4g+3}
  const int h = x >> 2;            // bn-half
  int mode, bm, bn;
  if (j < 16) {
    mode = 0; bm = (g << 2) + (j >> 2); bn = (h << 2) + (j & 3);
    gemm_tile(s1b_c, 2048, W0b, 2048, bm * BM, bn * BN, 2048, ldsA, ldsB, acc);
  } else if (j < 48) {
    mode = 1; const int u = j - 16; bm = (g << 2) + (u >> 3); bn = (h << 3) + (u & 7);
    gemm_tile(s2b_c, 2048, W1b, 2048, bm * BM, bn * BN, 2048, ldsA, ldsB, acc);
    gemm_tile(s0b_c, 1024, W0Tb, 1024, bm * BM, bn * BN, 1024, ldsA, ldsB, acc);
  } else {
    mode = 2; const int u = j - 48; bm = (g << 2) + (u >> 3); bn = (h << 3) + (u & 7);
    gemm_tile(s1b_c, 2048, W1Tb, 2048, bm * BM, bn * BN, 2048, ldsA, ldsB, acc);
  }

  const int t = threadIdx.x, wv = t >> 6, ln = t & 63;
  const int wr = wv >> 1, wc = wv & 1;
  const int rb = (ln >> 4) << 2, cc = ln & 15;
  const int m0 = bm * BM, n0 = bn * BN;

#pragma unroll
  for (int mt = 0; mt < 4; ++mt) {
#pragma unroll
    for (int nt = 0; nt < 4; ++nt) {
      const int gn = n0 + (wc << 6) + (nt << 4) + cc;
      float add = 0.f;
      if (mode == 0) add = b0[gn];
      else if (mode == 1) add = b1[gn];
#pragma unroll
      for (int r = 0; r < 4; ++r) {
        const int gm = m0 + (wr << 6) + (mt << 4) + rb + r;
        const float pre = acc[mt][nt][r];
        if (mode == 0) {
          const size_t ix = (size_t)gm * 1024 + gn;
          float nv = 0.8f * s0f[ix] + 0.2f * (pre + add);
          nv = fminf(fmaxf(nv, 0.f), 1.f);
          s0f[ix] = nv;
          s0b_n[ix] = f2bf(nv);
        } else if (mode == 1) {
          const size_t ix = (size_t)gm * 2048 + gn;
          float nv = 0.8f * s1f[ix] + 0.2f * (pre + add);
          nv = fminf(fmaxf(nv, 0.f), 1.f);
          s1f[ix] = nv;
          s1b_n[ix] = f2bf(nv);
        } else {
          const size_t ix = (size_t)gm * 2048 + gn;
          float nv = 0.8f * s2f[ix] + 0.2f * (pre + c2f[ix]);
          nv = fminf(fmaxf(nv, 0.f), 1.f);
          s2f[ix] = nv;
          s2b_n[ix] = f2bf(nv);
        }
      }
    }
  }
}

// c2 = data @ W2^T + b2 (step-invariant), fp32 result.
__global__ void c2_kernel(const uint16_t* __restrict__ datab,
                          const uint16_t* __restrict__ W2b,
                          const float* __restrict__ b2,
                          float* __restrict__ c2f)
{
  __shared__ uint16_t ldsA[BM * BK];
  __shared__ uint16_t ldsB[BN * BK];
  f32x4 acc[4][4];
  const f32x4 z = {0.f, 0.f, 0.f, 0.f};
#pragma unroll
  for (int i = 0; i < 4; ++i)
#pragma unroll
    for (int j = 0; j < 4; ++j) acc[i][j] = z;

  const int bm = blockIdx.x >> 4, bn = blockIdx.x & 15;
  gemm_tile(datab, 2048, W2b, 2048, bm * BM, bn * BN, 2048, ldsA, ldsB, acc);

  const int t = threadIdx.x, wv = t >> 6, ln = t & 63;
  const int wr = wv >> 1, wc = wv & 1;
  const int rb = (ln >> 4) << 2, cc = ln & 15;
  const int m0 = bm * BM, n0 = bn * BN;
#pragma unroll
  for (int mt = 0; mt < 4; ++mt)
#pragma unroll
    for (int nt = 0; nt < 4; ++nt) {
      const int gn = n0 + (wc << 6) + (nt << 4) + cc;
      const float bb = b2[gn];
#pragma unroll
      for (int r = 0; r < 4; ++r) {
        const int gm = m0 + (wr << 6) + (mt << 4) + rb + r;
        c2f[(size_t)gm * 2048 + gn] = acc[mt][nt][r] + bb;
      }
    }
}

// fp32 -> bf16 straight convert, 4 elems/thread.
__global__ void conv_k(const float* __restrict__ src, uint16_t* __restrict__ dst)
{
  const size_t i4 = ((size_t)blockIdx.x * 256 + threadIdx.x) << 2;
  const float4 v = *(const float4*)(src + i4);
  ushort4 o;
  o.x = f2bf(v.x); o.y = f2bf(v.y); o.z = f2bf(v.z); o.w = f2bf(v.w);
  *(ushort4*)(dst + i4) = o;
}

// fp32 -> bf16 transposed: dst[c*ldD + r] = bf16(src[r*ldS + c]).
__global__ void convT_k(const float* __restrict__ src, uint16_t* __restrict__ dst,
                        int ldS, int ldD)
{
  __shared__ uint16_t tile[32][33];
  const int r0 = blockIdx.y * 32, c0 = blockIdx.x * 32;
  tile[threadIdx.y][threadIdx.x] =
      f2bf(src[(size_t)(r0 + threadIdx.y) * ldS + c0 + threadIdx.x]);
  __syncthreads();
  dst[(size_t)(c0 + threadIdx.y) * ldD + r0 + threadIdx.x] = tile[threadIdx.x][threadIdx.y];
}

// fp32 input -> fp32 master (in d_out) + bf16 shadow. 4 elems/thread.
__global__ void init_state(const float* __restrict__ in,
                           float* __restrict__ sf, uint16_t* __restrict__ sb)
{
  const size_t i4 = ((size_t)blockIdx.x * 256 + threadIdx.x) << 2;
  const float4 v = *(const float4*)(in + i4);
  *(float4*)(sf + i4) = v;
  ushort4 o;
  o.x = f2bf(v.x); o.y = f2bf(v.y); o.z = f2bf(v.z); o.w = f2bf(v.w);
  *(ushort4*)(sb + i4) = o;
}

extern "C" void kernel_launch(void* const* d_in, const int* in_sizes, int n_in,
                              void* d_out, int out_size, void* d_ws, size_t ws_size,
                              hipStream_t stream) {
  const float* s0   = (const float*)d_in[0];
  const float* s1   = (const float*)d_in[1];
  const float* s2   = (const float*)d_in[2];
  const float* data = (const float*)d_in[3];
  const float* W0   = (const float*)d_in[4];
  const float* b0   = (const float*)d_in[5];
  const float* W1   = (const float*)d_in[6];
  const float* b1   = (const float*)d_in[7];
  const float* W2   = (const float*)d_in[8];
  const float* b2   = (const float*)d_in[9];

  // fp32 masters live directly in d_out: [s0 | s1 | s2].
  float* s0f = (float*)d_out;
  float* s1f = s0f + 2048ull * 1024;
  float* s2f = s1f + 2048ull * 2048;

  char* ws = (char*)d_ws;
  size_t off = 0;
  auto alloc = [&](size_t bytes) -> char* {
    char* p = ws + off; off += (bytes + 255) & ~(size_t)255; return p;
  };
  uint16_t* W0b    = (uint16_t*)alloc(1024ull * 2048 * 2);
  uint16_t* W0Tb   = (uint16_t*)alloc(2048ull * 1024 * 2);
  uint16_t* W1b    = (uint16_t*)alloc(2048ull * 2048 * 2);
  uint16_t* W1Tb   = (uint16_t*)alloc(2048ull * 2048 * 2);
  float*    c2f    = (float*)   alloc(2048ull * 2048 * 4);
  uint16_t* s0b[2] = { (uint16_t*)alloc(2048ull * 1024 * 2),
                       (uint16_t*)alloc(2048ull * 1024 * 2) };
  uint16_t* s1b[2] = { (uint16_t*)alloc(2048ull * 2048 * 2),
                       (uint16_t*)alloc(2048ull * 2048 * 2) };
  uint16_t* s2b[2] = { (uint16_t*)alloc(2048ull * 2048 * 2),
                       (uint16_t*)alloc(2048ull * 2048 * 2) };
  (void)ws_size; (void)in_sizes; (void)n_in; (void)out_size;

  // --- one-time weight prep (fp32 -> bf16) ---
  conv_k<<<1024 * 2048 / 1024, 256, 0, stream>>>(W0, W0b);
  conv_k<<<2048 * 2048 / 1024, 256, 0, stream>>>(W1, W1b);
  dim3 tb(32, 32);
  convT_k<<<dim3(64, 32), tb, 0, stream>>>(W0, W0Tb, 2048, 1024);
  convT_k<<<dim3(64, 64), tb, 0, stream>>>(W1, W1Tb, 2048, 2048);
  // data, W2 -> bf16 into step-"next" shadow buffers (fully overwritten by step 0
  // epilogue before step 1 reads them — safe temps).
  conv_k<<<2048 * 2048 / 1024, 256, 0, stream>>>(data, s1b[1]);
  conv_k<<<2048 * 2048 / 1024, 256, 0, stream>>>(W2, s2b[1]);
  c2_kernel<<<256, 256, 0, stream>>>(s1b[1], s2b[1], b2, c2f);

  // --- state init: fp32 masters (in d_out) + bf16 shadows ---
  init_state<<<2048 * 1024 / 1024, 256, 0, stream>>>(s0, s0f, s0b[0]);
  init_state<<<2048 * 2048 / 1024, 256, 0, stream>>>(s1, s1f, s1b[0]);
  init_state<<<2048 * 2048 / 1024, 256, 0, stream>>>(s2, s2f, s2b[0]);

  // --- 30 Jacobi relaxation steps, double-buffered bf16 shadows ---
  for (int it = 0; it < 30; ++it) {
    const int c = it & 1, n = c ^ 1;
    step_kernel<<<640, 256, 0, stream>>>(
        s0b[c], s1b[c], s2b[c], s0b[n], s1b[n], s2b[n],
        W0b, W0Tb, W1b, W1Tb, b0, b1, c2f, s0f, s1f, s2f);
  }
  // masters already in d_out — no output kernel needed.
}